// Round 1
// baseline (360.507 us; speedup 1.0000x reference)
//
#include <hip/hip_runtime.h>

// BMM_S8T_S8N_F16T: out[b,m,n] = fp16(alpha * sum_k A[b,m,k]*B[b,n,k])
// A: (B,M,K) int32 (int8-range), B: (B,N,K) int32, out: float (fp16 ref -> float* buffer)
// B=64, M=N=1024, K=128.
//
// Roofline: 268 MB fp32 write + 67 MB read => ~53 us floor @6.3 TB/s. Write-bound.
// Structure: 128x128 output tile / block (256 thr, 4 waves, 64x64 per wave),
// full K=128 staged packed-int8 in LDS (row stride 144B: 36 dwords, 2-way-max
// bank alias = free), mfma_i32_16x16x64_i8 x 2 K-steps, fp32 epilogue.

#define Mdim 1024
#define Ndim 1024
#define Kdim 128
#define TILE 128
#define LDS_STRIDE 144  // 128B row + 16B pad (keeps 16B alignment, breaks bank pow2)

using int32x4 = __attribute__((ext_vector_type(4))) int;

__global__ __launch_bounds__(256, 4)
void bmm_s8_kernel(const int* __restrict__ A, const int* __restrict__ Bm,
                   const float* __restrict__ alpha_p, float* __restrict__ out)
{
    __shared__ unsigned char As[TILE * LDS_STRIDE];
    __shared__ unsigned char Bs[TILE * LDS_STRIDE];

    const int t  = threadIdx.x;
    const int n0 = blockIdx.x * TILE;
    const int m0 = blockIdx.y * TILE;
    const int bz = blockIdx.z;

    const int* __restrict__ Ab = A  + (size_t)bz * Mdim * Kdim;
    const int* __restrict__ Bb = Bm + (size_t)bz * Ndim * Kdim;

    // ---- stage global int32 -> packed int8 in LDS ----
    // Tile = 128 rows x 128 k int32 = 4096 int4-chunks; 16 chunks/thread.
    // Chunk f: row = f>>5, element col = (f&31)*4. Per-instruction lanes are
    // 16B-contiguous (f = t + 256*j) -> coalesced 4 KB/wave-instr.
#pragma unroll
    for (int j = 0; j < 16; ++j) {
        const int f    = t + 256 * j;
        const int row  = f >> 5;
        const int colb = (f & 31) * 4;  // int32 col == packed byte offset

        const int32x4 va = *(const int32x4*)(Ab + (size_t)(m0 + row) * Kdim + colb);
        unsigned int pa = (unsigned)(va.x & 255)
                        | ((unsigned)(va.y & 255) << 8)
                        | ((unsigned)(va.z & 255) << 16)
                        | ((unsigned)(va.w & 255) << 24);
        *(unsigned int*)(&As[row * LDS_STRIDE + colb]) = pa;

        const int32x4 vb = *(const int32x4*)(Bb + (size_t)(n0 + row) * Kdim + colb);
        unsigned int pb = (unsigned)(vb.x & 255)
                        | ((unsigned)(vb.y & 255) << 8)
                        | ((unsigned)(vb.z & 255) << 16)
                        | ((unsigned)(vb.w & 255) << 24);
        *(unsigned int*)(&Bs[row * LDS_STRIDE + colb]) = pb;
    }
    __syncthreads();

    // ---- MFMA compute: wave w handles 64x64 sub-tile ----
    const int lane = t & 63;
    const int wave = t >> 6;
    const int wm = (wave >> 1) * 64;
    const int wn = (wave & 1) * 64;

    int32x4 acc[4][4];
#pragma unroll
    for (int mt = 0; mt < 4; ++mt)
#pragma unroll
        for (int nt = 0; nt < 4; ++nt)
            acc[mt][nt] = (int32x4){0, 0, 0, 0};

    // A-operand layout (16x16x64 i8): lane holds row (lane&15), 16 contiguous
    // k-bytes at koff (lane>>4)*16.
    const int lrow = lane & 15;
    const int koff = (lane >> 4) * 16;

#pragma unroll
    for (int ks = 0; ks < 2; ++ks) {
        int32x4 af[4], bf[4];
#pragma unroll
        for (int mt = 0; mt < 4; ++mt)
            af[mt] = *(const int32x4*)(&As[(wm + mt * 16 + lrow) * LDS_STRIDE + ks * 64 + koff]);
#pragma unroll
        for (int nt = 0; nt < 4; ++nt)
            bf[nt] = *(const int32x4*)(&Bs[(wn + nt * 16 + lrow) * LDS_STRIDE + ks * 64 + koff]);
#pragma unroll
        for (int mt = 0; mt < 4; ++mt)
#pragma unroll
            for (int nt = 0; nt < 4; ++nt)
                acc[mt][nt] = __builtin_amdgcn_mfma_i32_16x16x64_i8(
                    af[mt], bf[nt], acc[mt][nt], 0, 0, 0);
    }

    // ---- epilogue: alpha * acc -> fp32 out ----
    // C/D layout (16x16): col = lane&15, row = (lane>>4)*4 + reg  [m89/m121]
    const float alpha = alpha_p[0];
    const int crow = (lane >> 4) * 4;
    const int ccol = lane & 15;
    float* __restrict__ Ob = out + (size_t)bz * Mdim * Ndim;

#pragma unroll
    for (int mt = 0; mt < 4; ++mt)
#pragma unroll
        for (int nt = 0; nt < 4; ++nt) {
            const int n = n0 + wn + nt * 16 + ccol;
            const size_t base = (size_t)(m0 + wm + mt * 16 + crow) * Ndim + n;
#pragma unroll
            for (int r = 0; r < 4; ++r)
                Ob[base + (size_t)r * Ndim] = alpha * (float)acc[mt][nt][r];
        }
}

extern "C" void kernel_launch(void* const* d_in, const int* in_sizes, int n_in,
                              void* d_out, int out_size, void* d_ws, size_t ws_size,
                              hipStream_t stream) {
    const int*   a     = (const int*)d_in[0];
    const int*   b     = (const int*)d_in[1];
    const float* alpha = (const float*)d_in[2];
    float*       out   = (float*)d_out;

    const int batch = in_sizes[0] / (Mdim * Kdim);  // 64
    dim3 grid(Ndim / TILE, Mdim / TILE, batch);
    bmm_s8_kernel<<<grid, 256, 0, stream>>>(a, b, alpha, out);
}